// Round 14
// baseline (712.265 us; speedup 1.0000x reference)
//
#include <hip/hip_runtime.h>

#define BB 8
#define NN 8192
#define RR 2048
#define LL 4
#define TC 61
#define EPSF 1e-6f
#define BN (BB*NN)
#define OUTN (BN*3)
#define CH 32768

typedef unsigned short u16;
typedef unsigned int u32;
typedef _Float16 h2f __attribute__((ext_vector_type(2)));
typedef _Float16 h8 __attribute__((ext_vector_type(8)));
typedef float f4 __attribute__((ext_vector_type(4)));

__device__ __forceinline__ u32 packf16(float a, float b) {
  h2f h; h.x = (_Float16)a; h.y = (_Float16)b; return __builtin_bit_cast(u32, h);
}
__device__ __forceinline__ u16 f16b(float a) {
  _Float16 h = (_Float16)a; return __builtin_bit_cast(u16, h);
}
__device__ __forceinline__ float f162f(u16 h) { return (float)__builtin_bit_cast(_Float16, h); }
__device__ __forceinline__ float2 unpk(u32 a) {
  h2f h = __builtin_bit_cast(h2f, a); return make_float2((float)h.x, (float)h.y);
}
__device__ __forceinline__ int kmax_of(int n) {
  int aatom = n & 3, rres = n >> 2;
  return (aatom==0) ? (rres==0 ? 2 : 3)
       : (aatom==1) ? 3
       : (aatom==2) ? (rres==RR-1 ? 3 : 4) : 2;
}

__global__ __launch_bounds__(256) void k_const(float* out, float v) {
  int i = blockIdx.x*256 + threadIdx.x;
  if (i < OUTN) out[i] = v;
}

// ---------- weight pre-pack (MFMA B-fragment regions only) ----------
// W16 index space (u32):
// [139264..188416): QKV B-frags   [l][mat0..5][8 fb][256]
// [188416..278528): odfb B-frags  [l][Wo0 8fb][Wo1 8fb][Wff1 8fb][ffa 32fb][ffb 32fb] x 256
struct WSrc { const float* m[11]; };
__global__ __launch_bounds__(256) void k_prep(WSrc s, u32* W16) {
  int idx = blockIdx.x*256 + threadIdx.x;   // 139264 items
  if (idx >= 139264) return;
  int i = idx + 139264;
  if (i < 188416) {                // QKV B-frags
    int j2 = i - 139264;
    int l = j2 / 12288, rem = j2 % 12288;
    int m = rem >> 11, r2 = rem & 2047;
    int fb = r2 >> 8, li = r2 & 255;
    int nt = fb >> 1, kc = fb & 1;
    int lane = li >> 2, j = li & 3;
    int c2 = kc*16 + (lane>>4)*4 + j;
    int e  = nt*16 + (lane & 15);
    const float* src = s.m[m] + l*4096;
    W16[i] = packf16(src[(2*c2)*64 + e], src[(2*c2+1)*64 + e]);
  } else {                         // odfb B-frags
    int j2 = i - 188416;
    int l = j2 / 22528, rem = j2 % 22528;
    if (rem < 6144) {              // Wo0 / Wo1 / Wff1 (64x64)
      int msel = 6 + (rem >> 11);
      int r2 = rem & 2047;
      int fb = r2 >> 8, li = r2 & 255;
      const float* srcb = s.m[msel] + l*4096;
      int nt = fb >> 1, kc = fb & 1;
      int lane = li >> 2, j = li & 3;
      int c2 = kc*16 + (lane>>4)*4 + j;
      int e  = nt*16 + (lane & 15);
      W16[i] = packf16(srcb[(2*c2)*64 + e], srcb[(2*c2+1)*64 + e]);
    } else if (rem < 14336) {      // ffa (64x256)
      int r2 = rem - 6144;
      int fb = r2 >> 8, li = r2 & 255;
      const float* srcb = s.m[9] + l*16384;
      int nt = fb >> 1, kc = fb & 1;
      int lane = li >> 2, j = li & 3;
      int c2 = kc*16 + (lane>>4)*4 + j;
      int e  = nt*16 + (lane & 15);
      W16[i] = packf16(srcb[(2*c2)*256 + e], srcb[(2*c2+1)*256 + e]);
    } else {                       // ffb (256x64), fb = nt*8+kc
      int r2 = rem - 14336;
      int fb = r2 >> 8, li = r2 & 255;
      const float* srcb = s.m[10] + l*16384;
      int nt = fb >> 3, kc = fb & 7;
      int lane = li >> 2, j = li & 3;
      int c2 = kc*16 + (lane>>4)*4 + j;
      int e  = nt*16 + (lane & 15);
      W16[i] = packf16(srcb[(2*c2)*64 + e], srcb[(2*c2+1)*64 + e]);
    }
  }
}

// ---------- time embedding MLP ----------
__global__ __launch_bounds__(128) void k_te(const float* t, const float* w1, const float* b1,
                                            const float* w2, const float* b2, float* te2) {
  __shared__ float s0[128], s1[128];
  int j = threadIdx.x;
  for (int b = 0; b < BB; ++b) {
    float tv = t[b];
    int i = j & 63;
    float fr = expf(-9.210340371976184f * (float)i * (1.0f/64.0f));
    float em = tv * fr;
    s0[j] = (j < 64) ? sinf(em) : cosf(em);
    __syncthreads();
    float acc = b1[j];
    for (int i2 = 0; i2 < 128; ++i2) acc += s0[i2] * w1[i2*128 + j];
    s1[j] = acc / (1.f + expf(-acc));
    __syncthreads();
    if (j < TC) {
      float a2 = b2[j];
      for (int i2 = 0; i2 < 128; ++i2) a2 += s1[i2] * w2[i2*TC + j];
      te2[b*TC + j] = a2;
    }
    __syncthreads();
  }
}

// ---------- init f0p/f1p + rhat ----------
__global__ __launch_bounds__(256) void k_init(const float* x, const float* win1, const int* nbr,
                                              const float* te2, u32* f0p, u32* f1p, u16* rhat) {
  int tok = blockIdx.x*8 + (threadIdx.x >> 5);
  int c2 = threadIdx.x & 31;
  int b = tok >> 13, n = tok & (NN-1);
  float x0 = x[tok*3+0], x1 = x[tok*3+1], x2 = x[tok*3+2];
  int ca = 2*c2, cb = 2*c2+1;
  float va = (ca < TC) ? te2[b*TC + ca] : (ca == 61 ? x0 : (ca == 62 ? x1 : x2));
  float vb = (cb < TC) ? te2[b*TC + cb] : (cb == 61 ? x0 : (cb == 62 ? x1 : x2));
  f0p[tok*32 + c2] = packf16(va, vb);
  float wa = win1[ca], wb = win1[cb];
  f1p[(tok*3+0)*32 + c2] = packf16(x0*wa, x0*wb);
  f1p[(tok*3+1)*32 + c2] = packf16(x1*wa, x1*wb);
  f1p[(tok*3+2)*32 + c2] = packf16(x2*wa, x2*wb);
  if (c2 < 4) {
    int tj = b*NN + nbr[n*4 + c2];
    float rx = x[tj*3+0] - x0, ry = x[tj*3+1] - x1, rz = x[tj*3+2] - x2;
    float ir = rsqrtf(rx*rx + ry*ry + rz*rz + EPSF);
    rhat[(tok*4+c2)*3 + 0] = f16b(rx * ir);
    rhat[(tok*4+c2)*3 + 1] = f16b(ry * ir);
    rhat[(tok*4+c2)*3 + 2] = f16b(rz * ir);
  }
}

// ---------- kA: LN/vnorm + QKV via MFMA (wave = 16 tokens) ----------
__global__ __launch_bounds__(256) void k_qkv(const u32* W16, int l,
    const u32* f0p, const u32* f1p, int tokb,
    u16* Q0, u16* K0, u16* V0, u16* Q1, u16* K1, u16* V1) {
  __shared__ u32 S[9216];
  int tid = threadIdx.x, wv = tid >> 6, lane = tid & 63;
  u32* sg0 = S + wv*2304;
  u32* sg1 = sg0 + 576;
  int tl16 = (blockIdx.x*4 + wv)*16;
  {
    int t = lane >> 2, q = lane & 3;
    int gt = tokb + tl16 + t;
    u32 r0[8];
    *(uint4*)(r0)     = *(const uint4*)(f0p + (size_t)gt*32 + q*8);
    *(uint4*)(r0 + 4) = *(const uint4*)(f0p + (size_t)gt*32 + q*8 + 4);
    float s = 0.f, s2 = 0.f;
#pragma unroll
    for (int i = 0; i < 8; ++i) { float2 p = unpk(r0[i]); s += p.x + p.y; s2 += p.x*p.x + p.y*p.y; }
    s  += __shfl_xor(s, 1, 64);  s  += __shfl_xor(s, 2, 64);
    s2 += __shfl_xor(s2, 1, 64); s2 += __shfl_xor(s2, 2, 64);
    float mu = s*(1.f/64.f);
    float ri = rsqrtf(fmaxf(s2*(1.f/64.f)-mu*mu, 0.f) + EPSF);
#pragma unroll
    for (int i = 0; i < 8; ++i) {
      float2 p = unpk(r0[i]);
      sg0[t*36 + q*8 + i] = packf16((p.x-mu)*ri, (p.y-mu)*ri);
    }
    u32 r1[3][8]; float ss = 0.f;
#pragma unroll
    for (int v = 0; v < 3; ++v) {
      *(uint4*)(r1[v])     = *(const uint4*)(f1p + (size_t)(gt*3+v)*32 + q*8);
      *(uint4*)(r1[v] + 4) = *(const uint4*)(f1p + (size_t)(gt*3+v)*32 + q*8 + 4);
#pragma unroll
      for (int i = 0; i < 8; ++i) { float2 p = unpk(r1[v][i]); ss += p.x*p.x + p.y*p.y; }
    }
    ss += __shfl_xor(ss, 1, 64); ss += __shfl_xor(ss, 2, 64);
    float vs = rsqrtf(ss*(1.f/64.f) + EPSF);
#pragma unroll
    for (int v = 0; v < 3; ++v)
#pragma unroll
      for (int i = 0; i < 8; ++i) {
        float2 p = unpk(r1[v][i]);
        sg1[(v*16+t)*36 + q*8 + i] = packf16(p.x*vs, p.y*vs);
      }
  }
  __syncthreads();
  int arow = lane & 15, aq = lane >> 4;
  h8 ag0[2], ag1[3][2];
#pragma unroll
  for (int kc = 0; kc < 2; ++kc)
    ag0[kc] = __builtin_bit_cast(h8, *(const uint4*)(sg0 + arow*36 + kc*16 + aq*4));
#pragma unroll
  for (int v = 0; v < 3; ++v)
#pragma unroll
    for (int kc = 0; kc < 2; ++kc)
      ag1[v][kc] = __builtin_bit_cast(h8, *(const uint4*)(sg1 + (v*16+arow)*36 + kc*16 + aq*4));
  const u32* base = W16 + 139264 + l*12288;
  int mb = (lane>>4)*4, ncol = lane & 15;
  auto proj = [&](const u32* pm, const h8* afr, u16* out, int vstride, int vv) {
    u32* outp = (u32*)out;
#pragma unroll
    for (int nt = 0; nt < 4; ++nt) {
      f4 acc = {0.f, 0.f, 0.f, 0.f};
#pragma unroll
      for (int kc = 0; kc < 2; ++kc) {
        uint4 wb = *(const uint4*)(pm + (nt*2+kc)*256 + lane*4);
        acc = __builtin_amdgcn_mfma_f32_16x16x32_f16(afr[kc], __builtin_bit_cast(h8, wb), acc, 0, 0, 0);
      }
#pragma unroll
      for (int r = 0; r < 4; ++r) {
        int tok = tl16 + mb + r;
        float val = acc[r];
        float par = __shfl_xor(val, 1, 64);
        if (!(ncol & 1))
          outp[((size_t)tok*vstride + vv)*32 + nt*8 + (ncol>>1)] = packf16(val, par);
      }
    }
  };
  proj(base + 0*2048, ag0, Q0, 1, 0);
  proj(base + 1*2048, ag0, K0, 1, 0);
  proj(base + 2*2048, ag0, V0, 1, 0);
#pragma unroll
  for (int v = 0; v < 3; ++v) proj(base + 3*2048, ag1[v], Q1, 3, v);
#pragma unroll
  for (int v = 0; v < 3; ++v) proj(base + 4*2048, ag1[v], K1, 3, v);
#pragma unroll
  for (int v = 0; v < 3; ++v) proj(base + 5*2048, ag1[v], V1, 3, v);
}

// ---------- kC: attention + out-proj + FF, fully fused (wave = 16 tokens) ----------
__global__ __launch_bounds__(256) void k_odfb(const u32* W16, int l,
    const u16* Q0, const u16* K0, const u16* V0,
    const u16* Q1, const u16* K1, const u16* V1,
    const int* nbr, const u16* rhat, int tokb, u32* f0p, u32* f1p) {
  __shared__ u32 S[11008];          // 4 waves x 2752, all regions wave-private
  int tid = threadIdx.x, wv = tid >> 6, lane = tid & 63;
  u32* sw  = S + wv*2752;
  // attn: o1 A-frag rows sw[0..1728), o0 rows sw[1728..2304)
  // f1:   sg1 sw[0..1728) (after a1 regs loaded)
  // f0:   gg  sw[1728..2304) (after a0 regs loaded)
  // ffa/ffb: hh sw[0..2176) (after sg1 dead, ga regs loaded)
  int tl16 = (blockIdx.x*4 + wv)*16;
  int arow = lane & 15, aq = lane >> 4;
  int quad = lane >> 4, ncol = lane & 15, mb = quad*4;
  const u32* Wf  = W16 + 188416 + l*22528;
  const u32* po0f = Wf, *po1f = Wf + 2048, *pf1f = Wf + 4096, *paf = Wf + 6144, *pbf = Wf + 14336;

  // ---- attn phase: lane = channel, loop 16 tokens ----
  {
    u16* oh = (u16*)sw;
    int e = lane;
    for (int t = 0; t < 16; ++t) {
      int tl = tl16 + t;
      int gt = tokb + tl;
      int n = gt & (NN-1);
      int km = kmax_of(n);
      int base = gt - n - tokb;
      int tk[4];
#pragma unroll
      for (int k = 0; k < 4; ++k) tk[k] = nbr[n*4+k] + base;
      float q0 = f162f(Q0[(size_t)tl*64+e]);
      float q1[3];
#pragma unroll
      for (int v = 0; v < 3; ++v) q1[v] = f162f(Q1[(size_t)(tl*3+v)*64+e]);
      float k0r[4], v0r[4], k1r[4][3], v1r[4][3], rh[4][3];
#pragma unroll
      for (int k = 0; k < 4; ++k) {
        k0r[k] = f162f(K0[(size_t)tk[k]*64+e]);
        v0r[k] = f162f(V0[(size_t)tk[k]*64+e]);
#pragma unroll
        for (int v = 0; v < 3; ++v) {
          k1r[k][v] = f162f(K1[(size_t)(tk[k]*3+v)*64+e]);
          v1r[k][v] = f162f(V1[(size_t)(tk[k]*3+v)*64+e]);
          rh[k][v]  = f162f(rhat[(size_t)(gt*4+k)*3+v]);
        }
      }
      float p[4];
#pragma unroll
      for (int k = 0; k < 4; ++k)
        p[k] = q0*k0r[k] + q1[0]*k1r[k][0] + q1[1]*k1r[k][1] + q1[2]*k1r[k][2];
#pragma unroll
      for (int m = 1; m < 16; m <<= 1) {
#pragma unroll
        for (int k = 0; k < 4; ++k) p[k] += __shfl_xor(p[k], m, 64);
      }
      float mx = -1e30f;
#pragma unroll
      for (int k = 0; k < 4; ++k) { p[k] *= 0.25f; if (k < km) mx = fmaxf(mx, p[k]); }
      float aw[4], ssum = 0.f;
#pragma unroll
      for (int k = 0; k < 4; ++k) { aw[k] = (k < km) ? expf(p[k]-mx) : 0.f; ssum += aw[k]; }
      float inv = 1.f / ssum;
      float O0 = 0.f, O1[3] = {0.f,0.f,0.f};
#pragma unroll
      for (int k = 0; k < 4; ++k) {
        float a = aw[k]*inv;
        float vd = v1r[k][0]*rh[k][0] + v1r[k][1]*rh[k][1] + v1r[k][2]*rh[k][2];
        O0 += a*(v0r[k] + vd);
#pragma unroll
        for (int v = 0; v < 3; ++v) O1[v] += a*(v1r[k][v] + v0r[k]*rh[k][v]);
      }
      oh[3456 + t*72 + e] = f16b(O0);
#pragma unroll
      for (int v = 0; v < 3; ++v) oh[(v*16 + t)*72 + e] = f16b(O1[v]);
    }
  }
  __syncthreads();

  // ---- f1 path: Wo1 + residual ----
  h8 a1[3][2];
#pragma unroll
  for (int v = 0; v < 3; ++v)
#pragma unroll
    for (int kc = 0; kc < 2; ++kc)
      a1[v][kc] = __builtin_bit_cast(h8, *(const uint4*)(sw + (v*16+arow)*36 + kc*16 + aq*4));
  h8 a0[2];
#pragma unroll
  for (int kc = 0; kc < 2; ++kc)
    a0[kc] = __builtin_bit_cast(h8, *(const uint4*)(sw + 1728 + arow*36 + kc*16 + aq*4));
  float f1m[3][4][4];
#pragma unroll
  for (int v = 0; v < 3; ++v)
#pragma unroll
    for (int nt = 0; nt < 4; ++nt) {
      f4 acc = {0.f,0.f,0.f,0.f};
#pragma unroll
      for (int kc = 0; kc < 2; ++kc) {
        uint4 wb = *(const uint4*)(po1f + (nt*2+kc)*256 + lane*4);
        acc = __builtin_amdgcn_mfma_f32_16x16x32_f16(a1[v][kc], __builtin_bit_cast(h8, wb), acc, 0, 0, 0);
      }
#pragma unroll
      for (int r = 0; r < 4; ++r) {
        int gt = tokb + tl16 + mb + r;
        float2 p = unpk(f1p[((size_t)gt*3+v)*32 + nt*8 + (ncol>>1)]);
        f1m[v][nt][r] = acc[r] + ((ncol&1) ? p.y : p.x);
      }
    }
  float vs[4];
#pragma unroll
  for (int r = 0; r < 4; ++r) {
    float ss = 0.f;
#pragma unroll
    for (int v = 0; v < 3; ++v)
#pragma unroll
      for (int nt = 0; nt < 4; ++nt) ss += f1m[v][nt][r]*f1m[v][nt][r];
    ss += __shfl_xor(ss, 1, 64); ss += __shfl_xor(ss, 2, 64);
    ss += __shfl_xor(ss, 4, 64); ss += __shfl_xor(ss, 8, 64);
    vs[r] = rsqrtf(ss*(1.f/64.f) + EPSF);
  }
  {
    u16* sg1h = (u16*)sw;
#pragma unroll
    for (int v = 0; v < 3; ++v)
#pragma unroll
      for (int nt = 0; nt < 4; ++nt)
#pragma unroll
        for (int r = 0; r < 4; ++r)
          sg1h[v*1152 + (mb+r)*72 + nt*16 + ncol] = f16b(f1m[v][nt][r]*vs[r]);
  }
  __syncthreads();
  // ff1 + residual -> f1p
#pragma unroll
  for (int v = 0; v < 3; ++v)
#pragma unroll
    for (int nt = 0; nt < 4; ++nt) {
      f4 acc = {0.f,0.f,0.f,0.f};
#pragma unroll
      for (int kc = 0; kc < 2; ++kc) {
        h8 af = __builtin_bit_cast(h8, *(const uint4*)(sw + v*576 + arow*36 + kc*16 + aq*4));
        uint4 wb = *(const uint4*)(pf1f + (nt*2+kc)*256 + lane*4);
        acc = __builtin_amdgcn_mfma_f32_16x16x32_f16(af, __builtin_bit_cast(h8, wb), acc, 0, 0, 0);
      }
#pragma unroll
      for (int r = 0; r < 4; ++r) {
        int gt = tokb + tl16 + mb + r;
        float val = acc[r] + f1m[v][nt][r];
        float par = __shfl_xor(val, 1, 64);
        if (!(ncol & 1))
          f1p[((size_t)gt*3+v)*32 + nt*8 + (ncol>>1)] = packf16(val, par);
      }
    }
  __syncthreads();

  // ---- f0 path: Wo0 + residual ----
  float f0m[4][4];
#pragma unroll
  for (int nt = 0; nt < 4; ++nt) {
    f4 acc = {0.f,0.f,0.f,0.f};
#pragma unroll
    for (int kc = 0; kc < 2; ++kc) {
      uint4 wb = *(const uint4*)(po0f + (nt*2+kc)*256 + lane*4);
      acc = __builtin_amdgcn_mfma_f32_16x16x32_f16(a0[kc], __builtin_bit_cast(h8, wb), acc, 0, 0, 0);
    }
#pragma unroll
    for (int r = 0; r < 4; ++r) {
      int gt = tokb + tl16 + mb + r;
      float2 p = unpk(f0p[(size_t)gt*32 + nt*8 + (ncol>>1)]);
      f0m[nt][r] = acc[r] + ((ncol&1) ? p.y : p.x);
    }
  }
  float mu[4], ri[4];
#pragma unroll
  for (int r = 0; r < 4; ++r) {
    float s = 0.f, s2 = 0.f;
#pragma unroll
    for (int nt = 0; nt < 4; ++nt) { s += f0m[nt][r]; s2 += f0m[nt][r]*f0m[nt][r]; }
    s  += __shfl_xor(s, 1, 64);  s  += __shfl_xor(s, 2, 64);
    s  += __shfl_xor(s, 4, 64);  s  += __shfl_xor(s, 8, 64);
    s2 += __shfl_xor(s2, 1, 64); s2 += __shfl_xor(s2, 2, 64);
    s2 += __shfl_xor(s2, 4, 64); s2 += __shfl_xor(s2, 8, 64);
    mu[r] = s*(1.f/64.f);
    ri[r] = rsqrtf(fmaxf(s2*(1.f/64.f)-mu[r]*mu[r], 0.f) + EPSF);
  }
  {
    u16* gh = (u16*)(sw + 1728);
#pragma unroll
    for (int nt = 0; nt < 4; ++nt)
#pragma unroll
      for (int r = 0; r < 4; ++r)
        gh[(mb+r)*72 + nt*16 + ncol] = f16b((f0m[nt][r]-mu[r])*ri[r]);
  }
  __syncthreads();
  // ffa + silu -> hh at sw[0..2176)
  {
    h8 ga[2];
#pragma unroll
    for (int kc = 0; kc < 2; ++kc)
      ga[kc] = __builtin_bit_cast(h8, *(const uint4*)(sw + 1728 + arow*36 + kc*16 + aq*4));
    u16* hhh = (u16*)sw;
#pragma unroll
    for (int nt16 = 0; nt16 < 16; ++nt16) {
      f4 acc = {0.f,0.f,0.f,0.f};
#pragma unroll
      for (int kc = 0; kc < 2; ++kc) {
        uint4 wb = *(const uint4*)(paf + (nt16*2+kc)*256 + lane*4);
        acc = __builtin_amdgcn_mfma_f32_16x16x32_f16(ga[kc], __builtin_bit_cast(h8, wb), acc, 0, 0, 0);
      }
#pragma unroll
      for (int r = 0; r < 4; ++r) {
        float a = acc[r];
        hhh[(mb+r)*272 + nt16*16 + ncol] = f16b(a / (1.f + expf(-a)));
      }
    }
  }
  __syncthreads();
  // ffb + residual -> f0p
#pragma unroll
  for (int nt = 0; nt < 4; ++nt) {
    f4 acc = {0.f,0.f,0.f,0.f};
#pragma unroll
    for (int kc = 0; kc < 8; ++kc) {
      h8 af = __builtin_bit_cast(h8, *(const uint4*)(sw + arow*136 + kc*16 + aq*4));
      uint4 wb = *(const uint4*)(pbf + (nt*8+kc)*256 + lane*4);
      acc = __builtin_amdgcn_mfma_f32_16x16x32_f16(af, __builtin_bit_cast(h8, wb), acc, 0, 0, 0);
    }
#pragma unroll
    for (int r = 0; r < 4; ++r) {
      int gt = tokb + tl16 + mb + r;
      float val = acc[r] + f0m[nt][r];
      float par = __shfl_xor(val, 1, 64);
      if (!(ncol & 1))
        f0p[(size_t)gt*32 + nt*8 + (ncol>>1)] = packf16(val, par);
    }
  }
}

// ---------- final score ----------
__global__ __launch_bounds__(256) void k_final(const u32* f1p, const float* wout, const float* bout, float* out) {
  int tok = blockIdx.x*4 + (threadIdx.x >> 6);
  int lane = threadIdx.x & 63;
  float p[3];
#pragma unroll
  for (int v = 0; v < 3; ++v) {
    float2 pr = unpk(f1p[(size_t)(tok*3+v)*32 + (lane>>1)]);
    float x = ((lane & 1) ? pr.y : pr.x) * wout[v*64 + lane];
#pragma unroll
    for (int m = 1; m < 64; m <<= 1) x += __shfl_xor(x, m, 64);
    p[v] = x;
  }
  if (lane < 3) out[tok*3 + lane] = p[lane] + bout[lane];
}

extern "C" void kernel_launch(void* const* d_in, const int* in_sizes, int n_in,
                              void* d_out, int out_size, void* d_ws, size_t ws_size,
                              hipStream_t stream) {
  float* out = (float*)d_out;
  static const int exp23[23] = {196608,196608,8,32768,32768,16384,128,7808,61,64,
                                16384,16384,16384,16384,16384,16384,16384,16384,
                                65536,65536,16384,192,3};
  bool ok23 = (n_in == 23), ok22 = (n_in == 22);
  int bad = -1;
  if (ok23) {
    for (int i = 0; i < 23; ++i) if (in_sizes[i] != exp23[i]) { ok23 = false; bad = i; break; }
  }
  if (!ok23 && ok22) {
    for (int i = 0; i < 22; ++i) {
      int want = (i == 0) ? exp23[0] : exp23[i+1];
      if (in_sizes[i] != want) { ok22 = false; if (bad < 0) bad = i; break; }
    }
  } else ok22 = false;
  if (!ok23 && !ok22) {
    k_const<<<768, 256, 0, stream>>>(out, (float)(3000 + (bad < 0 ? 100 + n_in : bad)));
    return;
  }
  int sh = ok23 ? 0 : -1;
  const int* nbr = (const int*)d_in[3 + sh];
  const float* F[20];
  F[0] = (const float*)d_in[0];
  F[1] = (const float*)d_in[2 + sh];
  for (int j = 0; j < 18; ++j) F[2 + j] = (const float*)d_in[5 + sh + j];

  char* ws = (char*)d_ws;
  u32*   W16  = (u32*)ws;                           // 278528 u32 = 1,114,112 B
  float* te2  = (float*)(ws + 1114112);             // 2,048 B
  u16*   rhat = (u16*)(ws + 1116160);               // 1,572,864 B
  u32*   f0p  = (u32*)(ws + 2689024);               // 8,388,608 B
  u32*   f1p  = (u32*)(ws + 11077632);              // 25,165,824 B
  char*  cb   = ws + 36243456;                      // chunk area
  u16* Q0 = (u16*)(cb + 0);
  u16* K0 = (u16*)(cb + 4194304);
  u16* V0 = (u16*)(cb + 8388608);
  u16* Q1 = (u16*)(cb + 12582912);
  u16* K1 = (u16*)(cb + 25165824);
  u16* V1 = (u16*)(cb + 37748736);

  WSrc s;
  s.m[0]=F[7]; s.m[1]=F[8]; s.m[2]=F[9]; s.m[3]=F[10]; s.m[4]=F[11]; s.m[5]=F[12];
  s.m[6]=F[13]; s.m[7]=F[14]; s.m[8]=F[17]; s.m[9]=F[15]; s.m[10]=F[16];

  k_prep<<<544, 256, 0, stream>>>(s, W16);
  k_te<<<1, 128, 0, stream>>>(F[1], F[2], F[3], F[4], F[5], te2);
  k_init<<<BN/8, 256, 0, stream>>>(F[0], F[6], nbr, te2, f0p, f1p, rhat);
  for (int c = 0; c < 2; ++c) {
    int tokb = c * CH;
    for (int l = 0; l < LL; ++l) {
      k_qkv<<<CH/64, 256, 0, stream>>>(W16, l, f0p, f1p, tokb, Q0, K0, V0, Q1, K1, V1);
      k_odfb<<<CH/64, 256, 0, stream>>>(W16, l, Q0, K0, V0, Q1, K1, V1, nbr, rhat, tokb, f0p, f1p);
    }
  }
  k_final<<<BN/4, 256, 0, stream>>>(f1p, F[18], F[19], out);
}